// Round 14
// baseline (690.847 us; speedup 1.0000x reference)
//
#include <hip/hip_runtime.h>
#include <hip/hip_bf16.h>
#include <hip/hip_cooperative_groups.h>
#include <math.h>

namespace cg = cooperative_groups;

#define SEQ 2048
#define BATCH 4
#define HDIM 256
#define NHEAD 4
#define FFN_DIM 1024
#define MTOT (BATCH*SEQ)   // 8192

typedef __attribute__((ext_vector_type(8))) short bf16x8;
typedef __attribute__((ext_vector_type(4))) float f32x4;

__device__ __forceinline__ bf16x8 cvt8(const float* p)
{
    float4 a = *(const float4*)p;
    float4 b = *(const float4*)(p + 4);
    union { bf16x8 v; __hip_bfloat16 e[8]; } u;
    u.e[0] = __float2bfloat16(a.x); u.e[1] = __float2bfloat16(a.y);
    u.e[2] = __float2bfloat16(a.z); u.e[3] = __float2bfloat16(a.w);
    u.e[4] = __float2bfloat16(b.x); u.e[5] = __float2bfloat16(b.y);
    u.e[6] = __float2bfloat16(b.z); u.e[7] = __float2bfloat16(b.w);
    return u.v;
}

// ---------------------------------------------------------------------------
// Weights f32 -> bf16, re-laid out in MFMA-FRAGMENT TILES:
//   W[N][K] -> tiles [N/16][K/32][lane=0..63][8], where
//   lane = ((k>>3)&3)*16 + (row&15), elem = k&7.
// ---------------------------------------------------------------------------
__global__ __launch_bounds__(256)
void cvt_all(const float* __restrict__ w_in, const float* __restrict__ w_out,
             const float* __restrict__ qkv_w, const float* __restrict__ out_w,
             const float* __restrict__ ff1_w, const float* __restrict__ ff2_w,
             __hip_bfloat16* __restrict__ wb)
{
    int i = blockIdx.x * 256 + threadIdx.x;   // grid 1216 -> exact (311296 thr)
    size_t e = (size_t)i * 8;

    const float* srcbase; size_t rbase; int kshift;  // K = 1<<kshift
    if (e < 720896) {
        if (e < 65536)       { srcbase = w_in;  rbase = 0;      kshift = 8; }
        else if (e < 131072) { srcbase = w_out; rbase = 65536;  kshift = 8; }
        else                 { srcbase = qkv_w; rbase = 131072; kshift = 8; }
    } else if (e < 917504)   { srcbase = out_w; rbase = 720896; kshift = 8; }
    else if (e < 1703936)    { srcbase = ff1_w; rbase = 917504; kshift = 8; }
    else                     { srcbase = ff2_w; rbase = 1703936; kshift = 10; }

    size_t local = e - rbase;
    int K = 1 << kshift;
    int row = (int)(local >> kshift);
    int k   = (int)(local & (K - 1));          // multiple of 8

    size_t dst = rbase
               + ((size_t)(row >> 4) * (K >> 5) + (k >> 5)) * 512
               + (size_t)((((k >> 3) & 3) << 4) | (row & 15)) * 8;

    *(bf16x8*)(wb + dst) = cvt8(srcbase + local);
}

// fragment-tile load helper: W swizzled with inner-dim K, n0 16-aligned
__device__ __forceinline__ bf16x8 fragW(const short* W, int n0, int k0, int K, int lane)
{
    return *(const bf16x8*)(W + ((size_t)(n0 >> 4) * (K >> 5) + (k0 >> 5)) * 512 + lane * 8);
}

// head-split scatter index (Q/K fragment-tiled, V dense)
__device__ __forceinline__ size_t qkv_idx(int row, int col)
{
    int sec = col >> 8, hd = (col >> 6) & 3, d = col & 63;
    int srow = row & (SEQ - 1);
    size_t base = (size_t)sec * 2097152
                + (size_t)(((row >> 11) << 2) | hd) * 131072;
    if (sec < 2)
        return base + (size_t)(srow >> 4) * 1024 + (size_t)(d >> 5) * 512
             + (size_t)((((d >> 3) & 3) << 4) | (srow & 15)) * 8 + (d & 7);
    return base + (size_t)srow * 64 + d;
}

// LN of 32x256 fp32 LDS tile -> bf16 LDS tile (each of 16 waves: 2 rows)
__device__ __forceinline__ void ln_rows(const float (*H)[260], short (*A)[264],
                                        const float* __restrict__ g,
                                        const float* __restrict__ bl,
                                        int wave, int lane)
{
    float4 gv = *(const float4*)(g + lane * 4);
    float4 bv = *(const float4*)(bl + lane * 4);
    #pragma unroll
    for (int u = 0; u < 2; u++) {
        float4 xv = *(const float4*)&H[wave*2 + u][lane*4];
        float ss2 = xv.x + xv.y + xv.z + xv.w;
        #pragma unroll
        for (int off = 32; off >= 1; off >>= 1) ss2 += __shfl_xor(ss2, off);
        float mu = ss2 * (1.0f/256.0f);
        float d0 = xv.x-mu, d1 = xv.y-mu, d2 = xv.z-mu, d3 = xv.w-mu;
        float v = d0*d0 + d1*d1 + d2*d2 + d3*d3;
        #pragma unroll
        for (int off = 32; off >= 1; off >>= 1) v += __shfl_xor(v, off);
        float rstd = rsqrtf(v * (1.0f/256.0f) + 1e-5f);
        union { short e[4]; uint2 w2; } o;
        o.e[0] = (short)__bfloat16_as_ushort(__float2bfloat16(d0*rstd*gv.x + bv.x));
        o.e[1] = (short)__bfloat16_as_ushort(__float2bfloat16(d1*rstd*gv.y + bv.y));
        o.e[2] = (short)__bfloat16_as_ushort(__float2bfloat16(d2*rstd*gv.z + bv.z));
        o.e[3] = (short)__bfloat16_as_ushort(__float2bfloat16(d3*rstd*gv.w + bv.w));
        *(uint2*)&A[wave*2 + u][lane*4] = o.w2;
    }
}

// ---------------------------------------------------------------------------
// MEGAKERNEL: cooperative, grid (64,4) = 256 blocks = 1 block/CU, 1024 thr.
// Each block owns one (batch, 32-row) stripe; h lives in LDS the whole time.
//   embed -> H_lds ; LN1_0 + qkv_0 -> qkvd0 ; grid.sync
//   3x { attention(qkvd src) + proj + residual(H_lds) + LN2 + FFN + residual;
//        l<2: LN1_{l+1} + qkv -> other qkvd buffer, grid.sync
//        l=2: LNf + out-GEMM -> d_out }
// ---------------------------------------------------------------------------
struct AttnLDS {
    __align__(16) __hip_bfloat16 Vt[64][128];
    __align__(16) __hip_bfloat16 Pl[32][96];
    float sm[2][32], ss[2][32];
};

__global__ __launch_bounds__(1024)
void mega(const float* __restrict__ X,
          const __hip_bfloat16* __restrict__ wb,
          const float* __restrict__ qkv_b,
          const float* __restrict__ out_b,
          const float* __restrict__ ln1_g, const float* __restrict__ ln1_b,
          const float* __restrict__ ln2_g, const float* __restrict__ ln2_b,
          const float* __restrict__ ff1_b, const float* __restrict__ ff2_b,
          const float* __restrict__ lnf_g, const float* __restrict__ lnf_b,
          const float* __restrict__ b_out,
          float* __restrict__ outp,
          __hip_bfloat16* __restrict__ qkvd0,
          __hip_bfloat16* __restrict__ qkvd1)
{
    __shared__ union SMem {
        AttnLDS asl[4];                                   // 92160 B (attention)
        struct {
            __align__(16) short A[32][264];               // LN out (bf16)
            __align__(16) short Z[2][32][264];            // FFN hidden, dbuf
        } f;                                              // 50688 B (FFN)
    } U;
    __shared__ __align__(16) short att_lds[32][264];
    __shared__ __align__(16) float H_lds[32][260];

    cg::grid_group grid = cg::this_grid();

    int tid  = threadIdx.x;
    int wave = tid >> 6, lane = tid & 63;
    int grp  = wave >> 2, w4 = wave & 3, ltid = tid & 255;
    int b    = blockIdx.y, i0 = blockIdx.x * 32;
    int klo  = i0 - 32;

    int lr = lane & 15, hi = lane >> 4;
    int cc = lane & 15, quad = lane >> 4;
    int qh = w4 & 1, seg = w4 >> 1;
    int qoff = qh * 16 + quad * 4;

    const short* wbs = (const short*)wb;

    // ======== EMBED: H_lds = 16*(x @ w_in^T) + PE (wave owns 16 cols) ======
    {
        const float* px0 = X + (size_t)(b*SEQ + i0 + lr) * HDIM + hi * 8;
        const float* px1 = px0 + (size_t)16 * HDIM;
        f32x4 acc[2];
        acc[0] = (f32x4){0.f,0.f,0.f,0.f}; acc[1] = (f32x4){0.f,0.f,0.f,0.f};
        #pragma unroll
        for (int k0 = 0; k0 < 256; k0 += 32) {
            bf16x8 a0 = cvt8(px0 + k0);
            bf16x8 a1 = cvt8(px1 + k0);
            bf16x8 b0 = fragW(wbs, wave*16, k0, 256, lane);   // w_in at offset 0
            acc[0] = __builtin_amdgcn_mfma_f32_16x16x32_bf16(a0, b0, acc[0], 0,0,0);
            acc[1] = __builtin_amdgcn_mfma_f32_16x16x32_bf16(a1, b0, acc[1], 0,0,0);
        }
        int col = wave*16 + cc;
        int i2 = col & ~1;
        float freq = __expf((float)i2 * (-9.210340371976184f / 256.0f));
        #pragma unroll
        for (int mt = 0; mt < 2; mt++)
            #pragma unroll
            for (int r = 0; r < 4; r++) {
                int srow = i0 + mt*16 + quad*4 + r;
                float arg = (float)srow * freq;
                float pe = (col & 1) ? __cosf(arg) : __sinf(arg);
                H_lds[mt*16 + quad*4 + r][col] = 16.0f*acc[mt][r] + pe;
            }
    }
    __syncthreads();

    // ======== layer-0 qkv: LN1_0(H_lds) -> A ; A @ qkv_w^T -> qkvd0 ========
    ln_rows(H_lds, U.f.A, ln1_g, ln1_b, wave, lane);
    __syncthreads();
    {
        const short* Wts = wbs + 131072;   // qkv_w layer 0
        f32x4 qa[2][3];
        #pragma unroll
        for (int mt = 0; mt < 2; mt++)
            #pragma unroll
            for (int nt = 0; nt < 3; nt++)
                qa[mt][nt] = (f32x4){0.f,0.f,0.f,0.f};
        #pragma unroll
        for (int k0 = 0; k0 < 256; k0 += 32) {
            bf16x8 a0 = *(const bf16x8*)&U.f.A[lr][k0 + hi*8];
            bf16x8 a1 = *(const bf16x8*)&U.f.A[16 + lr][k0 + hi*8];
            #pragma unroll
            for (int nt = 0; nt < 3; nt++) {
                bf16x8 wf = fragW(Wts, wave*48 + nt*16, k0, 256, lane);
                qa[0][nt] = __builtin_amdgcn_mfma_f32_16x16x32_bf16(a0, wf, qa[0][nt], 0,0,0);
                qa[1][nt] = __builtin_amdgcn_mfma_f32_16x16x32_bf16(a1, wf, qa[1][nt], 0,0,0);
            }
        }
        #pragma unroll
        for (int nt = 0; nt < 3; nt++) {
            int col = wave*48 + nt*16 + cc;
            float bv = qkv_b[col];
            #pragma unroll
            for (int mt = 0; mt < 2; mt++)
                #pragma unroll
                for (int r = 0; r < 4; r++) {
                    int row = b * SEQ + i0 + mt*16 + quad*4 + r;
                    qkvd0[qkv_idx(row, col)] = __float2bfloat16(qa[mt][nt][r] + bv);
                }
        }
    }
    __threadfence();
    grid.sync();

    // ======== 3 transformer layers ========
    #pragma unroll 1
    for (int l = 0; l < 3; l++) {
        const short* Qbase = (const short*)((l == 1) ? qkvd1 : qkvd0);
        const short* ows = wbs + 720896 + (size_t)l * 65536;
        const short* W1s = wbs + 917504 + (size_t)l * 262144;
        const short* W2s = wbs + 1703936 + (size_t)l * 262144;
        const float* ob  = out_b + l * HDIM;
        const float* b1  = ff1_b + l * FFN_DIM;
        const float* b2  = ff2_b + l * HDIM;
        const float* g2  = ln2_g + l * HDIM;
        const float* bl2 = ln2_b + l * HDIM;

        int hd = grp;
        AttnLDS& S = U.asl[grp];
        const short* Qd = Qbase + (size_t)(b * 4 + hd) * 131072;
        const short* Kd = Qd + 2097152;
        const short* Vd = Qd + 4194304;

        // -------- entry prefetch --------
        int vm = ltid & 7, vrl = ltid >> 3, vdp = vm * 8;
        bf16x8 vr[3];
        #pragma unroll
        for (int rr = 0; rr < 3; rr++) {
            int j = klo + rr * 32 + vrl;
            j = j < 0 ? 0 : (j > SEQ - 1 ? SEQ - 1 : j);
            vr[rr] = *(const bf16x8*)(Vd + (size_t)j * 64 + vdp);
        }
        bf16x8 qf[2];
        #pragma unroll
        for (int ds = 0; ds < 2; ds++)
            qf[ds] = *(const bf16x8*)(Qd + (size_t)((i0 >> 4) + qh) * 1024 + ds * 512 + lane * 8);
        bf16x8 kf[3][2];
        #pragma unroll
        for (int t = 0; t < 3; t++) {
            int jt = (klo + seg * 48 + t * 16) >> 4;
            jt = jt < 0 ? 0 : (jt > 127 ? 127 : jt);
            kf[t][0] = *(const bf16x8*)(Kd + (size_t)jt * 1024 + lane * 8);
            kf[t][1] = *(const bf16x8*)(Kd + (size_t)jt * 1024 + 512 + lane * 8);
        }

        // -------- attention --------
        { // scatter V^T
            union { bf16x8 v; short e[8]; } u;
            #pragma unroll
            for (int rr = 0; rr < 3; rr++) {
                int row = rr * 32 + vrl;
                int colp = row ^ (vm << 3);
                u.v = vr[rr];
                #pragma unroll
                for (int jj = 0; jj < 8; jj++)
                    *(short*)&S.Vt[vdp + jj][colp] = u.e[jj];
            }
        }

        f32x4 sacc[3];
        #pragma unroll
        for (int t = 0; t < 3; t++) {
            f32x4 a = (f32x4){0.f,0.f,0.f,0.f};
            a = __builtin_amdgcn_mfma_f32_16x16x32_bf16(qf[0], kf[t][0], a, 0,0,0);
            a = __builtin_amdgcn_mfma_f32_16x16x32_bf16(qf[1], kf[t][1], a, 0,0,0);
            sacc[t] = a;
        }

        float s[3][4];
        #pragma unroll
        for (int t = 0; t < 3; t++) {
            int koff = seg * 48 + t * 16 + cc;
            int jj = klo + koff;
            #pragma unroll
            for (int r = 0; r < 4; r++) {
                int rel = koff - (qoff + r);
                bool ok = (jj >= 0) && (jj < SEQ) && (rel >= 0) && (rel <= 64);
                s[t][r] = ok ? sacc[t][r] * 0.125f : -1e30f;
            }
        }

        float mrow[4], srow[4];
        #pragma unroll
        for (int r = 0; r < 4; r++)
            mrow[r] = fmaxf(fmaxf(s[0][r], s[1][r]), s[2][r]);
        #pragma unroll
        for (int off = 8; off >= 1; off >>= 1)
            #pragma unroll
            for (int r = 0; r < 4; r++)
                mrow[r] = fmaxf(mrow[r], __shfl_xor(mrow[r], off));
        #pragma unroll
        for (int r = 0; r < 4; r++)
            srow[r] = __expf(s[0][r]-mrow[r]) + __expf(s[1][r]-mrow[r]) + __expf(s[2][r]-mrow[r]);
        #pragma unroll
        for (int off = 8; off >= 1; off >>= 1)
            #pragma unroll
            for (int r = 0; r < 4; r++)
                srow[r] += __shfl_xor(srow[r], off);
        if (cc == 0) {
            #pragma unroll
            for (int r = 0; r < 4; r++) { S.sm[seg][qoff+r] = mrow[r]; S.ss[seg][qoff+r] = srow[r]; }
        }
        __syncthreads();

        float Mr[4], inv[4];
        #pragma unroll
        for (int r = 0; r < 4; r++) {
            float m0 = S.sm[0][qoff+r], m1 = S.sm[1][qoff+r];
            float M = fmaxf(m0, m1);
            float dn = S.ss[0][qoff+r] * __expf(m0 - M) + S.ss[1][qoff+r] * __expf(m1 - M);
            Mr[r] = M; inv[r] = 1.0f / dn;
        }
        #pragma unroll
        for (int t = 0; t < 3; t++)
            #pragma unroll
            for (int r = 0; r < 4; r++)
                S.Pl[qoff+r][seg*48 + t*16 + cc] = __float2bfloat16(__expf(s[t][r]-Mr[r]) * inv[r]);
        __syncthreads();

        // prefetch proj weight fragments (hidden under PV)
        bf16x8 owf[8];
        {
            const short* op = ows + (size_t)wave * 8 * 512 + lane * 8;
            #pragma unroll
            for (int i = 0; i < 8; i++)
                owf[i] = *(const bf16x8*)(op + i * 512);
        }

        // O = P @ V -> att_lds
        {
            f32x4 oacc[2];
            oacc[0] = (f32x4){0.f,0.f,0.f,0.f}; oacc[1] = (f32x4){0.f,0.f,0.f,0.f};
            #pragma unroll
            for (int ks = 0; ks < 3; ks++) {
                int kk = ks * 32;
                bf16x8 pf = *(const bf16x8*)&S.Pl[qh*16 + lr][kk + hi*8];
                #pragma unroll
                for (int dt = 0; dt < 2; dt++) {
                    int d = seg*32 + dt*16 + lr;
                    int colb = (kk + hi*8) ^ (((d >> 3) & 7) << 3);
                    bf16x8 vf = *(const bf16x8*)&S.Vt[d][colb];
                    oacc[dt] = __builtin_amdgcn_mfma_f32_16x16x32_bf16(pf, vf, oacc[dt], 0,0,0);
                }
            }
            #pragma unroll
            for (int dt = 0; dt < 2; dt++) {
                int col = hd*64 + seg*32 + dt*16 + cc;
                #pragma unroll
                for (int r = 0; r < 4; r++)
                    att_lds[qoff + r][col] =
                        (short)__bfloat16_as_ushort(__float2bfloat16(oacc[dt][r]));
            }
        }
        __syncthreads();

        // -------- proj + residual -> H_lds (wave owns 16 cols) --------
        {
            f32x4 acc[2];
            acc[0] = (f32x4){0.f,0.f,0.f,0.f}; acc[1] = (f32x4){0.f,0.f,0.f,0.f};
            #pragma unroll
            for (int i = 0; i < 8; i++) {
                bf16x8 a0 = *(const bf16x8*)&att_lds[lr][i*32 + hi*8];
                bf16x8 a1 = *(const bf16x8*)&att_lds[16 + lr][i*32 + hi*8];
                acc[0] = __builtin_amdgcn_mfma_f32_16x16x32_bf16(a0, owf[i], acc[0], 0,0,0);
                acc[1] = __builtin_amdgcn_mfma_f32_16x16x32_bf16(a1, owf[i], acc[1], 0,0,0);
            }
            float bv = ob[wave*16 + cc];
            #pragma unroll
            for (int mt = 0; mt < 2; mt++)
                #pragma unroll
                for (int r = 0; r < 4; r++)
                    H_lds[mt*16 + quad*4 + r][wave*16 + cc] += acc[mt][r] + bv;
        }

        // prologue: prefetch W1 chunk 0 (hidden under barrier + LN2)
        bf16x8 w1f[8];
        {
            const short* wp = W1s + (size_t)wave * 8 * 512 + lane * 8;
            #pragma unroll
            for (int i = 0; i < 8; i++)
                w1f[i] = *(const bf16x8*)(wp + i * 512);
        }
        __syncthreads();

        // -------- LN2(H_lds) -> A --------
        ln_rows(H_lds, U.f.A, g2, bl2, wave, lane);
        __syncthreads();

        // -------- FFN --------
        f32x4 acc2[2];
        acc2[0] = (f32x4){0.f,0.f,0.f,0.f}; acc2[1] = (f32x4){0.f,0.f,0.f,0.f};

        #pragma unroll 1
        for (int kk = 0; kk < 4; kk++) {
            bf16x8 w2f[8];
            {
                const short* wp = W2s + (size_t)(wave * 32 + kk * 8) * 512 + lane * 8;
                #pragma unroll
                for (int i = 0; i < 8; i++)
                    w2f[i] = *(const bf16x8*)(wp + i * 512);
            }

            f32x4 acc1[2];
            acc1[0] = (f32x4){0.f,0.f,0.f,0.f}; acc1[1] = (f32x4){0.f,0.f,0.f,0.f};
            #pragma unroll
            for (int i = 0; i < 8; i++) {
                bf16x8 af0 = *(const bf16x8*)&U.f.A[lr][i*32 + hi*8];
                bf16x8 af1 = *(const bf16x8*)&U.f.A[16 + lr][i*32 + hi*8];
                acc1[0] = __builtin_amdgcn_mfma_f32_16x16x32_bf16(af0, w1f[i], acc1[0], 0,0,0);
                acc1[1] = __builtin_amdgcn_mfma_f32_16x16x32_bf16(af1, w1f[i], acc1[1], 0,0,0);
            }

            {
                int col = wave*16 + cc;
                float bb = b1[kk*256 + col];
                #pragma unroll
                for (int mt = 0; mt < 2; mt++)
                    #pragma unroll
                    for (int r = 0; r < 4; r++) {
                        float z = fmaxf(acc1[mt][r] + bb, 0.f);
                        U.f.Z[kk & 1][mt*16 + quad*4 + r][col] =
                            (short)__bfloat16_as_ushort(__float2bfloat16(z));
                    }
            }
            __syncthreads();

            {
                int nk = (kk < 3) ? kk + 1 : 3;
                const short* wp = W1s + (size_t)(nk * 16 + wave) * 8 * 512 + lane * 8;
                #pragma unroll
                for (int i = 0; i < 8; i++)
                    w1f[i] = *(const bf16x8*)(wp + i * 512);
            }

            #pragma unroll
            for (int i = 0; i < 8; i++) {
                bf16x8 zf0 = *(const bf16x8*)&U.f.Z[kk & 1][lr][i*32 + hi*8];
                bf16x8 zf1 = *(const bf16x8*)&U.f.Z[kk & 1][16 + lr][i*32 + hi*8];
                acc2[0] = __builtin_amdgcn_mfma_f32_16x16x32_bf16(zf0, w2f[i], acc2[0], 0,0,0);
                acc2[1] = __builtin_amdgcn_mfma_f32_16x16x32_bf16(zf1, w2f[i], acc2[1], 0,0,0);
            }
            // Z[kk&1] overwritten only at kk+2, after the kk+1 barrier.
        }

        // -------- residual: H_lds += FF2 + b2 --------
        {
            int col = wave*16 + cc;
            float bb = b2[col];
            #pragma unroll
            for (int mt = 0; mt < 2; mt++)
                #pragma unroll
                for (int r = 0; r < 4; r++) {
                    int rowl = mt*16 + quad*4 + r;
                    H_lds[rowl][col] = H_lds[rowl][col] + acc2[mt][r] + bb;
                }
        }
        __syncthreads();

        // -------- tail LN + GEMM --------
        const float* gt = (l < 2) ? (ln1_g + (l+1)*HDIM) : lnf_g;
        const float* bt = (l < 2) ? (ln1_b + (l+1)*HDIM) : lnf_b;
        ln_rows(H_lds, U.f.A, gt, bt, wave, lane);
        __syncthreads();

        if (l < 2) {
            // next layer's qkv (wave owns 48 cols) -> other buffer
            const short* Wts = wbs + 131072 + (size_t)(l+1) * 196608;
            const float* btb = qkv_b + (l+1) * 768;
            __hip_bfloat16* qdst = (l == 0) ? qkvd1 : qkvd0;

            f32x4 qa[2][3];
            #pragma unroll
            for (int mt = 0; mt < 2; mt++)
                #pragma unroll
                for (int nt = 0; nt < 3; nt++)
                    qa[mt][nt] = (f32x4){0.f,0.f,0.f,0.f};
            #pragma unroll
            for (int k0 = 0; k0 < 256; k0 += 32) {
                bf16x8 a0 = *(const bf16x8*)&U.f.A[lr][k0 + hi*8];
                bf16x8 a1 = *(const bf16x8*)&U.f.A[16 + lr][k0 + hi*8];
                #pragma unroll
                for (int nt = 0; nt < 3; nt++) {
                    bf16x8 wf = fragW(Wts, wave*48 + nt*16, k0, 256, lane);
                    qa[0][nt] = __builtin_amdgcn_mfma_f32_16x16x32_bf16(a0, wf, qa[0][nt], 0,0,0);
                    qa[1][nt] = __builtin_amdgcn_mfma_f32_16x16x32_bf16(a1, wf, qa[1][nt], 0,0,0);
                }
            }
            #pragma unroll
            for (int nt = 0; nt < 3; nt++) {
                int col = wave*48 + nt*16 + cc;
                float bv = btb[col];
                #pragma unroll
                for (int mt = 0; mt < 2; mt++)
                    #pragma unroll
                    for (int r = 0; r < 4; r++) {
                        int row = b * SEQ + i0 + mt*16 + quad*4 + r;
                        qdst[qkv_idx(row, col)] = __float2bfloat16(qa[mt][nt][r] + bv);
                    }
            }
            __threadfence();
            grid.sync();
        } else {
            // out = A @ w_out^T + b_out (wave owns 16 cols)
            bf16x8 wf[8];
            const short* wp = wbs + 65536 + (size_t)wave * 8 * 512 + lane * 8;
            #pragma unroll
            for (int i = 0; i < 8; i++)
                wf[i] = *(const bf16x8*)(wp + i * 512);

            f32x4 oa[2];
            oa[0] = (f32x4){0.f,0.f,0.f,0.f}; oa[1] = (f32x4){0.f,0.f,0.f,0.f};
            #pragma unroll
            for (int i = 0; i < 8; i++) {
                bf16x8 a0 = *(const bf16x8*)&U.f.A[lr][i*32 + hi*8];
                bf16x8 a1 = *(const bf16x8*)&U.f.A[16 + lr][i*32 + hi*8];
                oa[0] = __builtin_amdgcn_mfma_f32_16x16x32_bf16(a0, wf[i], oa[0], 0,0,0);
                oa[1] = __builtin_amdgcn_mfma_f32_16x16x32_bf16(a1, wf[i], oa[1], 0,0,0);
            }
            int col = wave*16 + cc;
            float bb = b_out[col];
            #pragma unroll
            for (int mt = 0; mt < 2; mt++)
                #pragma unroll
                for (int r = 0; r < 4; r++) {
                    int row = b * SEQ + i0 + mt*16 + quad*4 + r;
                    outp[(size_t)row * HDIM + col] = oa[mt][r] + bb;
                }
        }
    }
}

// ---------------------------------------------------------------------------
extern "C" void kernel_launch(void* const* d_in, const int* in_sizes, int n_in,
                              void* d_out, int out_size, void* d_ws, size_t ws_size,
                              hipStream_t stream)
{
    const float* x     = (const float*)d_in[0];
    const float* w_in  = (const float*)d_in[1];
    const float* w_out = (const float*)d_in[2];
    const float* b_out = (const float*)d_in[3];
    const float* qkv_w = (const float*)d_in[4];
    const float* qkv_b = (const float*)d_in[5];
    const float* out_w = (const float*)d_in[6];
    const float* out_b = (const float*)d_in[7];
    const float* ln1_g = (const float*)d_in[8];
    const float* ln1_b = (const float*)d_in[9];
    const float* ln2_g = (const float*)d_in[10];
    const float* ln2_b = (const float*)d_in[11];
    const float* ff1_w = (const float*)d_in[12];
    const float* ff1_b = (const float*)d_in[13];
    const float* ff2_w = (const float*)d_in[14];
    const float* ff2_b = (const float*)d_in[15];
    const float* lnf_g = (const float*)d_in[16];
    const float* lnf_b = (const float*)d_in[17];

    char* ws = (char*)d_ws;
    __hip_bfloat16* qkvd0 = (__hip_bfloat16*)ws;               // 12.6 MB
    __hip_bfloat16* qkvd1 = (__hip_bfloat16*)(ws + 12582912);  // 12.6 MB
    __hip_bfloat16* wb    = (__hip_bfloat16*)(ws + 25165824);  // weights bf16 (~5 MB)

    cvt_all<<<1216, dim3(256), 0, stream>>>(w_in, w_out, qkv_w, out_w, ff1_w, ff2_w, wb);

    const float* Xp = x;
    const __hip_bfloat16* wbp = wb;
    float* outp = (float*)d_out;
    void* args[] = {
        (void*)&Xp, (void*)&wbp,
        (void*)&qkv_b, (void*)&out_b,
        (void*)&ln1_g, (void*)&ln1_b,
        (void*)&ln2_g, (void*)&ln2_b,
        (void*)&ff1_b, (void*)&ff2_b,
        (void*)&lnf_g, (void*)&lnf_b,
        (void*)&b_out, (void*)&outp,
        (void*)&qkvd0, (void*)&qkvd1,
    };
    hipLaunchCooperativeKernel((const void*)mega, dim3(SEQ/32, BATCH), dim3(1024),
                               args, 0, stream);
}

// Round 15
// 220.918 us; speedup vs baseline: 3.1272x; 3.1272x over previous
//
#include <hip/hip_runtime.h>
#include <hip/hip_bf16.h>
#include <math.h>

#define SEQ 2048
#define BATCH 4
#define HDIM 256
#define NHEAD 4
#define FFN_DIM 1024
#define MTOT (BATCH*SEQ)   // 8192

typedef __attribute__((ext_vector_type(8))) short bf16x8;
typedef __attribute__((ext_vector_type(4))) float f32x4;

__device__ __forceinline__ bf16x8 cvt8(const float* p)
{
    float4 a = *(const float4*)p;
    float4 b = *(const float4*)(p + 4);
    union { bf16x8 v; __hip_bfloat16 e[8]; } u;
    u.e[0] = __float2bfloat16(a.x); u.e[1] = __float2bfloat16(a.y);
    u.e[2] = __float2bfloat16(a.z); u.e[3] = __float2bfloat16(a.w);
    u.e[4] = __float2bfloat16(b.x); u.e[5] = __float2bfloat16(b.y);
    u.e[6] = __float2bfloat16(b.z); u.e[7] = __float2bfloat16(b.w);
    return u.v;
}

// ---------------------------------------------------------------------------
// Weights f32 -> bf16, re-laid out in MFMA-FRAGMENT TILES:
//   W[N][K] -> tiles [N/16][K/32][lane=0..63][8], where
//   lane = ((k>>3)&3)*16 + (row&15), elem = k&7.
// ---------------------------------------------------------------------------
__global__ __launch_bounds__(256)
void cvt_all(const float* __restrict__ w_in, const float* __restrict__ w_out,
             const float* __restrict__ qkv_w, const float* __restrict__ out_w,
             const float* __restrict__ ff1_w, const float* __restrict__ ff2_w,
             __hip_bfloat16* __restrict__ wb)
{
    int i = blockIdx.x * 256 + threadIdx.x;   // grid 1216 -> exact (311296 thr)
    size_t e = (size_t)i * 8;

    const float* srcbase; size_t rbase; int kshift;  // K = 1<<kshift
    if (e < 720896) {
        if (e < 65536)       { srcbase = w_in;  rbase = 0;      kshift = 8; }
        else if (e < 131072) { srcbase = w_out; rbase = 65536;  kshift = 8; }
        else                 { srcbase = qkv_w; rbase = 131072; kshift = 8; }
    } else if (e < 917504)   { srcbase = out_w; rbase = 720896; kshift = 8; }
    else if (e < 1703936)    { srcbase = ff1_w; rbase = 917504; kshift = 8; }
    else                     { srcbase = ff2_w; rbase = 1703936; kshift = 10; }

    size_t local = e - rbase;
    int K = 1 << kshift;
    int row = (int)(local >> kshift);
    int k   = (int)(local & (K - 1));          // multiple of 8

    size_t dst = rbase
               + ((size_t)(row >> 4) * (K >> 5) + (k >> 5)) * 512
               + (size_t)((((k >> 3) & 3) << 4) | (row & 15)) * 8;

    *(bf16x8*)(wb + dst) = cvt8(srcbase + local);
}

// fragment-tile load helper: W swizzled with inner-dim K, n0 16-aligned
__device__ __forceinline__ bf16x8 fragW(const short* W, int n0, int k0, int K, int lane)
{
    return *(const bf16x8*)(W + ((size_t)(n0 >> 4) * (K >> 5) + (k0 >> 5)) * 512 + lane * 8);
}

// head-split scatter index (Q/K fragment-tiled, V dense)
__device__ __forceinline__ size_t qkv_idx(int row, int col)
{
    int sec = col >> 8, hd = (col >> 6) & 3, d = col & 63;
    int srow = row & (SEQ - 1);
    size_t base = (size_t)sec * 2097152
                + (size_t)(((row >> 11) << 2) | hd) * 131072;
    if (sec < 2)
        return base + (size_t)(srow >> 4) * 1024 + (size_t)(d >> 5) * 512
             + (size_t)((((d >> 3) & 3) << 4) | (srow & 15)) * 8 + (d & 7);
    return base + (size_t)srow * 64 + d;
}

// LN of 32x256 fp32 LDS tile -> bf16 LDS tile (each of 16 waves: 2 rows)
__device__ __forceinline__ void ln_rows(const float (*H)[260], short (*A)[264],
                                        const float* __restrict__ g,
                                        const float* __restrict__ bl,
                                        int wave, int lane)
{
    float4 gv = *(const float4*)(g + lane * 4);
    float4 bv = *(const float4*)(bl + lane * 4);
    #pragma unroll
    for (int u = 0; u < 2; u++) {
        float4 xv = *(const float4*)&H[wave*2 + u][lane*4];
        float ss2 = xv.x + xv.y + xv.z + xv.w;
        #pragma unroll
        for (int off = 32; off >= 1; off >>= 1) ss2 += __shfl_xor(ss2, off);
        float mu = ss2 * (1.0f/256.0f);
        float d0 = xv.x-mu, d1 = xv.y-mu, d2 = xv.z-mu, d3 = xv.w-mu;
        float v = d0*d0 + d1*d1 + d2*d2 + d3*d3;
        #pragma unroll
        for (int off = 32; off >= 1; off >>= 1) v += __shfl_xor(v, off);
        float rstd = rsqrtf(v * (1.0f/256.0f) + 1e-5f);
        union { short e[4]; uint2 w2; } o;
        o.e[0] = (short)__bfloat16_as_ushort(__float2bfloat16(d0*rstd*gv.x + bv.x));
        o.e[1] = (short)__bfloat16_as_ushort(__float2bfloat16(d1*rstd*gv.y + bv.y));
        o.e[2] = (short)__bfloat16_as_ushort(__float2bfloat16(d2*rstd*gv.z + bv.z));
        o.e[3] = (short)__bfloat16_as_ushort(__float2bfloat16(d3*rstd*gv.w + bv.w));
        *(uint2*)&A[wave*2 + u][lane*4] = o.w2;
    }
}

// ---------------------------------------------------------------------------
// Fused embed + LN1_0 + layer-0 qkv. Grid (64,4), 1024 thr.
// H stays in LDS between embed and LN1 (no h re-read); h written once.
// ---------------------------------------------------------------------------
__global__ __launch_bounds__(1024)
void embed_qkv(const float* __restrict__ X,
               const __hip_bfloat16* __restrict__ wb,
               const float* __restrict__ ln1_g, const float* __restrict__ ln1_b,
               const float* __restrict__ qkv_b,
               float* __restrict__ h, __hip_bfloat16* __restrict__ qkvd)
{
    __shared__ __align__(16) float H_lds[32][260];
    __shared__ __align__(16) short A_lds[32][264];

    int tid = threadIdx.x, wave = tid >> 6, lane = tid & 63;
    int b = blockIdx.y, i0 = blockIdx.x * 32;
    int lr = lane & 15, hi = lane >> 4;
    int cc = lane & 15, quad = lane >> 4;
    const short* wbs = (const short*)wb;

    // embed: H_lds = 16*(x @ w_in^T) + PE (wave owns 16 cols); also write h
    {
        const float* px0 = X + (size_t)(b*SEQ + i0 + lr) * HDIM + hi * 8;
        const float* px1 = px0 + (size_t)16 * HDIM;
        f32x4 acc[2];
        acc[0] = (f32x4){0.f,0.f,0.f,0.f}; acc[1] = (f32x4){0.f,0.f,0.f,0.f};
        #pragma unroll
        for (int k0 = 0; k0 < 256; k0 += 32) {
            bf16x8 a0 = cvt8(px0 + k0);
            bf16x8 a1 = cvt8(px1 + k0);
            bf16x8 b0 = fragW(wbs, wave*16, k0, 256, lane);   // w_in at offset 0
            acc[0] = __builtin_amdgcn_mfma_f32_16x16x32_bf16(a0, b0, acc[0], 0,0,0);
            acc[1] = __builtin_amdgcn_mfma_f32_16x16x32_bf16(a1, b0, acc[1], 0,0,0);
        }
        int col = wave*16 + cc;
        int i2 = col & ~1;
        float freq = __expf((float)i2 * (-9.210340371976184f / 256.0f));
        #pragma unroll
        for (int mt = 0; mt < 2; mt++)
            #pragma unroll
            for (int r = 0; r < 4; r++) {
                int rowl = mt*16 + quad*4 + r;
                int srow = i0 + rowl;
                float arg = (float)srow * freq;
                float pe = (col & 1) ? __cosf(arg) : __sinf(arg);
                float v = 16.0f*acc[mt][r] + pe;
                H_lds[rowl][col] = v;
                h[(size_t)(b*SEQ + srow) * HDIM + col] = v;
            }
    }
    __syncthreads();

    ln_rows(H_lds, A_lds, ln1_g, ln1_b, wave, lane);
    __syncthreads();

    // qkv_0 = A @ qkv_w^T + qkv_b (wave owns 48 cols)
    {
        const short* Wts = wbs + 131072;   // qkv_w layer 0
        f32x4 qa[2][3];
        #pragma unroll
        for (int mt = 0; mt < 2; mt++)
            #pragma unroll
            for (int nt = 0; nt < 3; nt++)
                qa[mt][nt] = (f32x4){0.f,0.f,0.f,0.f};
        #pragma unroll
        for (int k0 = 0; k0 < 256; k0 += 32) {
            bf16x8 a0 = *(const bf16x8*)&A_lds[lr][k0 + hi*8];
            bf16x8 a1 = *(const bf16x8*)&A_lds[16 + lr][k0 + hi*8];
            #pragma unroll
            for (int nt = 0; nt < 3; nt++) {
                bf16x8 wf = fragW(Wts, wave*48 + nt*16, k0, 256, lane);
                qa[0][nt] = __builtin_amdgcn_mfma_f32_16x16x32_bf16(a0, wf, qa[0][nt], 0,0,0);
                qa[1][nt] = __builtin_amdgcn_mfma_f32_16x16x32_bf16(a1, wf, qa[1][nt], 0,0,0);
            }
        }
        #pragma unroll
        for (int nt = 0; nt < 3; nt++) {
            int col = wave*48 + nt*16 + cc;
            float bv = qkv_b[col];
            #pragma unroll
            for (int mt = 0; mt < 2; mt++)
                #pragma unroll
                for (int r = 0; r < 4; r++) {
                    int row = b * SEQ + i0 + mt*16 + quad*4 + r;
                    qkvd[qkv_idx(row, col)] = __float2bfloat16(qa[mt][nt][r] + bv);
                }
        }
    }
}

// ---------------------------------------------------------------------------
// FULLY FUSED layer tail, 1024 threads / 16 waves.
// TAIL=1: also computes NEXT layer's qkv into qkv_out (different buffer).
// TAIL=2: fuses final LNf + out-GEMM (writes d_out directly).
// ---------------------------------------------------------------------------
struct AttnLDS {
    __align__(16) __hip_bfloat16 Vt[64][128];
    __align__(16) __hip_bfloat16 Pl[32][96];
    float sm[2][32], ss[2][32];
};

template<int TAIL>
__global__ __launch_bounds__(1024)
void attn_ffn(const __hip_bfloat16* __restrict__ qkvd,
              const __hip_bfloat16* __restrict__ ow,   // fragment-tiled [256][256]
              const float* __restrict__ ob,
              float* __restrict__ h,
              const float* __restrict__ g, const float* __restrict__ bln,
              const __hip_bfloat16* __restrict__ W1, const float* __restrict__ b1,
              const __hip_bfloat16* __restrict__ W2, const float* __restrict__ b2,
              const float* __restrict__ gt, const float* __restrict__ bt,
              const __hip_bfloat16* __restrict__ Wt, const float* __restrict__ btb,
              float* __restrict__ outp, __hip_bfloat16* __restrict__ qkv_out)
{
    __shared__ union SMem {
        AttnLDS asl[4];                                   // 92160 B (attention)
        struct {
            __align__(16) short A[32][264];               // LN out (bf16)
            __align__(16) short Z[2][32][264];            // FFN hidden, dbuf
        } f;                                              // 50688 B (FFN)
    } U;
    __shared__ __align__(16) short att_lds[32][264];
    __shared__ __align__(16) float H_lds[32][260];

    int tid  = threadIdx.x;
    int wave = tid >> 6, lane = tid & 63;
    int grp  = wave >> 2, w4 = wave & 3, ltid = tid & 255;
    int b    = blockIdx.y, i0 = blockIdx.x * 32;
    int klo  = i0 - 32;

    int lr = lane & 15, hi = lane >> 4;
    int cc = lane & 15, quad = lane >> 4;

    int hd = grp;
    AttnLDS& S = U.asl[grp];
    const short* Qd = (const short*)qkvd + (size_t)(b * 4 + hd) * 131072;
    const short* Kd = Qd + 2097152;
    const short* Vd = Qd + 4194304;
    int qh = w4 & 1, seg = w4 >> 1;
    int qoff = qh * 16 + quad * 4;

    // ======== ENTRY PREFETCH ========
    int vm = ltid & 7, vrl = ltid >> 3, vdp = vm * 8;
    bf16x8 vr[3];
    #pragma unroll
    for (int rr = 0; rr < 3; rr++) {
        int j = klo + rr * 32 + vrl;
        j = j < 0 ? 0 : (j > SEQ - 1 ? SEQ - 1 : j);
        vr[rr] = *(const bf16x8*)(Vd + (size_t)j * 64 + vdp);
    }
    bf16x8 qf[2];
    #pragma unroll
    for (int ds = 0; ds < 2; ds++)
        qf[ds] = *(const bf16x8*)(Qd + (size_t)((i0 >> 4) + qh) * 1024 + ds * 512 + lane * 8);
    bf16x8 kf[3][2];
    #pragma unroll
    for (int t = 0; t < 3; t++) {
        int jt = (klo + seg * 48 + t * 16) >> 4;
        jt = jt < 0 ? 0 : (jt > 127 ? 127 : jt);
        kf[t][0] = *(const bf16x8*)(Kd + (size_t)jt * 1024 + lane * 8);
        kf[t][1] = *(const bf16x8*)(Kd + (size_t)jt * 1024 + 512 + lane * 8);
    }
    float hold[2][4];
    {
        const float* hp = h + (size_t)(b * SEQ + i0) * HDIM + wave * 16 + cc;
        #pragma unroll
        for (int mt = 0; mt < 2; mt++)
            #pragma unroll
            for (int r = 0; r < 4; r++)
                hold[mt][r] = hp[(size_t)(mt*16 + quad*4 + r) * HDIM];
    }

    // ======== phase 1: attention ========
    { // scatter V^T
        union { bf16x8 v; short e[8]; } u;
        #pragma unroll
        for (int rr = 0; rr < 3; rr++) {
            int row = rr * 32 + vrl;
            int colp = row ^ (vm << 3);
            u.v = vr[rr];
            #pragma unroll
            for (int jj = 0; jj < 8; jj++)
                *(short*)&S.Vt[vdp + jj][colp] = u.e[jj];
        }
    }

    f32x4 sacc[3];
    #pragma unroll
    for (int t = 0; t < 3; t++) {
        f32x4 a = (f32x4){0.f,0.f,0.f,0.f};
        a = __builtin_amdgcn_mfma_f32_16x16x32_bf16(qf[0], kf[t][0], a, 0,0,0);
        a = __builtin_amdgcn_mfma_f32_16x16x32_bf16(qf[1], kf[t][1], a, 0,0,0);
        sacc[t] = a;
    }

    float s[3][4];
    #pragma unroll
    for (int t = 0; t < 3; t++) {
        int koff = seg * 48 + t * 16 + cc;
        int jj = klo + koff;
        #pragma unroll
        for (int r = 0; r < 4; r++) {
            int rel = koff - (qoff + r);
            bool ok = (jj >= 0) && (jj < SEQ) && (rel >= 0) && (rel <= 64);
            s[t][r] = ok ? sacc[t][r] * 0.125f : -1e30f;
        }
    }

    float mrow[4], srow[4];
    #pragma unroll
    for (int r = 0; r < 4; r++)
        mrow[r] = fmaxf(fmaxf(s[0][r], s[1][r]), s[2][r]);
    #pragma unroll
    for (int off = 8; off >= 1; off >>= 1)
        #pragma unroll
        for (int r = 0; r < 4; r++)
            mrow[r] = fmaxf(mrow[r], __shfl_xor(mrow[r], off));
    #pragma unroll
    for (int r = 0; r < 4; r++)
        srow[r] = __expf(s[0][r]-mrow[r]) + __expf(s[1][r]-mrow[r]) + __expf(s[2][r]-mrow[r]);
    #pragma unroll
    for (int off = 8; off >= 1; off >>= 1)
        #pragma unroll
        for (int r = 0; r < 4; r++)
            srow[r] += __shfl_xor(srow[r], off);
    if (cc == 0) {
        #pragma unroll
        for (int r = 0; r < 4; r++) { S.sm[seg][qoff+r] = mrow[r]; S.ss[seg][qoff+r] = srow[r]; }
    }
    __syncthreads();

    float Mr[4], inv[4];
    #pragma unroll
    for (int r = 0; r < 4; r++) {
        float m0 = S.sm[0][qoff+r], m1 = S.sm[1][qoff+r];
        float M = fmaxf(m0, m1);
        float dn = S.ss[0][qoff+r] * __expf(m0 - M) + S.ss[1][qoff+r] * __expf(m1 - M);
        Mr[r] = M; inv[r] = 1.0f / dn;
    }
    #pragma unroll
    for (int t = 0; t < 3; t++)
        #pragma unroll
        for (int r = 0; r < 4; r++)
            S.Pl[qoff+r][seg*48 + t*16 + cc] = __float2bfloat16(__expf(s[t][r]-Mr[r]) * inv[r]);
    __syncthreads();

    // prefetch proj weight fragments (hidden under PV)
    bf16x8 owf[8];
    {
        const short* op = (const short*)ow + (size_t)wave * 8 * 512 + lane * 8;
        #pragma unroll
        for (int i = 0; i < 8; i++)
            owf[i] = *(const bf16x8*)(op + i * 512);
    }

    // O = P @ V -> att_lds
    {
        f32x4 oacc[2];
        oacc[0] = (f32x4){0.f,0.f,0.f,0.f}; oacc[1] = (f32x4){0.f,0.f,0.f,0.f};
        #pragma unroll
        for (int ks = 0; ks < 3; ks++) {
            int kk = ks * 32;
            bf16x8 pf = *(const bf16x8*)&S.Pl[qh*16 + lr][kk + hi*8];
            #pragma unroll
            for (int dt = 0; dt < 2; dt++) {
                int d = seg*32 + dt*16 + lr;
                int colb = (kk + hi*8) ^ (((d >> 3) & 7) << 3);
                bf16x8 vf = *(const bf16x8*)&S.Vt[d][colb];
                oacc[dt] = __builtin_amdgcn_mfma_f32_16x16x32_bf16(pf, vf, oacc[dt], 0,0,0);
            }
        }
        #pragma unroll
        for (int dt = 0; dt < 2; dt++) {
            int col = hd*64 + seg*32 + dt*16 + cc;
            #pragma unroll
            for (int r = 0; r < 4; r++)
                att_lds[qoff + r][col] =
                    (short)__bfloat16_as_ushort(__float2bfloat16(oacc[dt][r]));
        }
    }
    __syncthreads();

    // ======== phase 2: proj + residual -> H_lds (wave owns 16 cols) ========
    {
        f32x4 acc[2];
        acc[0] = (f32x4){0.f,0.f,0.f,0.f}; acc[1] = (f32x4){0.f,0.f,0.f,0.f};
        #pragma unroll
        for (int i = 0; i < 8; i++) {
            bf16x8 a0 = *(const bf16x8*)&att_lds[lr][i*32 + hi*8];
            bf16x8 a1 = *(const bf16x8*)&att_lds[16 + lr][i*32 + hi*8];
            acc[0] = __builtin_amdgcn_mfma_f32_16x16x32_bf16(a0, owf[i], acc[0], 0,0,0);
            acc[1] = __builtin_amdgcn_mfma_f32_16x16x32_bf16(a1, owf[i], acc[1], 0,0,0);
        }
        float bv = ob[wave*16 + cc];
        #pragma unroll
        for (int mt = 0; mt < 2; mt++)
            #pragma unroll
            for (int r = 0; r < 4; r++)
                H_lds[mt*16 + quad*4 + r][wave*16 + cc] = hold[mt][r] + acc[mt][r] + bv;
    }

    // prologue: prefetch W1 chunk 0 (hidden under barrier + LN2)
    const short* W1s = (const short*)W1;
    const short* W2s = (const short*)W2;
    bf16x8 w1f[8];
    {
        const short* wp = W1s + (size_t)wave * 8 * 512 + lane * 8;
        #pragma unroll
        for (int i = 0; i < 8; i++)
            w1f[i] = *(const bf16x8*)(wp + i * 512);
    }
    __syncthreads();

    // ======== phase 3: LN2(H_lds) -> A ========
    ln_rows(H_lds, U.f.A, g, bln, wave, lane);
    __syncthreads();

    // ======== phase 4: FFN, Z dbuf, weights software-pipelined ========
    f32x4 acc2[2];
    acc2[0] = (f32x4){0.f,0.f,0.f,0.f}; acc2[1] = (f32x4){0.f,0.f,0.f,0.f};

    #pragma unroll 1
    for (int kk = 0; kk < 4; kk++) {
        bf16x8 w2f[8];
        {
            const short* wp = W2s + (size_t)(wave * 32 + kk * 8) * 512 + lane * 8;
            #pragma unroll
            for (int i = 0; i < 8; i++)
                w2f[i] = *(const bf16x8*)(wp + i * 512);
        }

        f32x4 acc1[2];
        acc1[0] = (f32x4){0.f,0.f,0.f,0.f}; acc1[1] = (f32x4){0.f,0.f,0.f,0.f};
        #pragma unroll
        for (int i = 0; i < 8; i++) {
            bf16x8 af0 = *(const bf16x8*)&U.f.A[lr][i*32 + hi*8];
            bf16x8 af1 = *(const bf16x8*)&U.f.A[16 + lr][i*32 + hi*8];
            acc1[0] = __builtin_amdgcn_mfma_f32_16x16x32_bf16(af0, w1f[i], acc1[0], 0,0,0);
            acc1[1] = __builtin_amdgcn_mfma_f32_16x16x32_bf16(af1, w1f[i], acc1[1], 0,0,0);
        }

        {
            int col = wave*16 + cc;
            float bb = b1[kk*256 + col];
            #pragma unroll
            for (int mt = 0; mt < 2; mt++)
                #pragma unroll
                for (int r = 0; r < 4; r++) {
                    float z = fmaxf(acc1[mt][r] + bb, 0.f);
                    U.f.Z[kk & 1][mt*16 + quad*4 + r][col] =
                        (short)__bfloat16_as_ushort(__float2bfloat16(z));
                }
        }
        __syncthreads();

        {
            int nk = (kk < 3) ? kk + 1 : 3;
            const short* wp = W1s + (size_t)(nk * 16 + wave) * 8 * 512 + lane * 8;
            #pragma unroll
            for (int i = 0; i < 8; i++)
                w1f[i] = *(const bf16x8*)(wp + i * 512);
        }

        #pragma unroll
        for (int i = 0; i < 8; i++) {
            bf16x8 zf0 = *(const bf16x8*)&U.f.Z[kk & 1][lr][i*32 + hi*8];
            bf16x8 zf1 = *(const bf16x8*)&U.f.Z[kk & 1][16 + lr][i*32 + hi*8];
            acc2[0] = __builtin_amdgcn_mfma_f32_16x16x32_bf16(zf0, w2f[i], acc2[0], 0,0,0);
            acc2[1] = __builtin_amdgcn_mfma_f32_16x16x32_bf16(zf1, w2f[i], acc2[1], 0,0,0);
        }
        // Z[kk&1] overwritten only at kk+2, after the kk+1 barrier.
    }

    // ======== tail ========
    {
        int col = wave*16 + cc;
        float bb = b2[col];
        #pragma unroll
        for (int mt = 0; mt < 2; mt++)
            #pragma unroll
            for (int r = 0; r < 4; r++) {
                int rowl = mt*16 + quad*4 + r;
                float v = H_lds[rowl][col] + acc2[mt][r] + bb;
                H_lds[rowl][col] = v;
                if (TAIL == 1) {
                    int row = b * SEQ + i0 + rowl;
                    h[(size_t)row * HDIM + col] = v;
                }
            }
    }
    __syncthreads();

    // tail LN (LN1 of next layer, or LNf)
    ln_rows(H_lds, U.f.A, gt, bt, wave, lane);
    __syncthreads();

    if (TAIL == 2) {
        // out = A @ w_out^T + b_out (wave owns 16 cols)
        bf16x8 wf[8];
        const short* wp = (const short*)Wt + (size_t)wave * 8 * 512 + lane * 8;
        #pragma unroll
        for (int i = 0; i < 8; i++)
            wf[i] = *(const bf16x8*)(wp + i * 512);

        f32x4 oa[2];
        oa[0] = (f32x4){0.f,0.f,0.f,0.f}; oa[1] = (f32x4){0.f,0.f,0.f,0.f};
        #pragma unroll
        for (int i = 0; i < 8; i++) {
            bf16x8 a0 = *(const bf16x8*)&U.f.A[lr][i*32 + hi*8];
            bf16x8 a1 = *(const bf16x8*)&U.f.A[16 + lr][i*32 + hi*8];
            oa[0] = __builtin_amdgcn_mfma_f32_16x16x32_bf16(a0, wf[i], oa[0], 0,0,0);
            oa[1] = __builtin_amdgcn_mfma_f32_16x16x32_bf16(a1, wf[i], oa[1], 0,0,0);
        }
        int col = wave*16 + cc;
        float bb = btb[col];
        #pragma unroll
        for (int mt = 0; mt < 2; mt++)
            #pragma unroll
            for (int r = 0; r < 4; r++) {
                int row = b * SEQ + i0 + mt*16 + quad*4 + r;
                outp[(size_t)row * HDIM + col] = oa[mt][r] + bb;
            }
    } else {
        // TAIL == 1: next layer's qkv = A @ Wt^T + btb (wave owns 48 cols)
        const short* Wts = (const short*)Wt;
        f32x4 qa[2][3];
        #pragma unroll
        for (int mt = 0; mt < 2; mt++)
            #pragma unroll
            for (int nt = 0; nt < 3; nt++)
                qa[mt][nt] = (f32x4){0.f,0.f,0.f,0.f};

        #pragma unroll
        for (int k0 = 0; k0 < 256; k0 += 32) {
            bf16x8 a0 = *(const bf16x8*)&U.f.A[lr][k0 + hi*8];
            bf16x8 a1 = *(const bf16x8*)&U.f.A[16 + lr][k0 + hi*8];
            #pragma unroll
            for (int nt = 0; nt < 3; nt++) {
                bf16x8 wf = fragW(Wts, wave*48 + nt*16, k0, 256, lane);
                qa[0][nt] = __builtin_amdgcn_mfma_f32_16x16x32_bf16(a0, wf, qa[0][nt], 0,0,0);
                qa[1][nt] = __builtin_amdgcn_mfma_f32_16x16x32_bf16(a1, wf, qa[1][nt], 0,0,0);
            }
        }
        #pragma unroll
        for (int nt = 0; nt < 3; nt++) {
            int col = wave*48 + nt*16 + cc;
            float bv = btb[col];
            #pragma unroll
            for (int mt = 0; mt < 2; mt++)
                #pragma unroll
                for (int r = 0; r < 4; r++) {
                    int row = b * SEQ + i0 + mt*16 + quad*4 + r;
                    qkv_out[qkv_idx(row, col)] = __float2bfloat16(qa[mt][nt][r] + bv);
                }
        }
    }
}

// ---------------------------------------------------------------------------
extern "C" void kernel_launch(void* const* d_in, const int* in_sizes, int n_in,
                              void* d_out, int out_size, void* d_ws, size_t ws_size,
                              hipStream_t stream)
{
    const float* x     = (const float*)d_in[0];
    const float* w_in  = (const float*)d_in[1];
    const float* w_out = (const float*)d_in[2];
    const float* b_out = (const float*)d_in[3];
    const float* qkv_w = (const float*)d_in[4];
    const float* qkv_b = (const float*)d_in[5];
    const float* out_w = (const float*)d_in[6];
    const float* out_b = (const float*)d_in[7];
    const float* ln1_g = (const float*)d_in[8];
    const float* ln1_b = (const float*)d_in[9];
    const float* ln2_g = (const float*)d_in[10];
    const float* ln2_b = (const float*)d_in[11];
    const float* ff1_w = (const float*)d_in[12];
    const float* ff1_b = (const float*)d_in[13];
    const float* ff2_w = (const float*)d_in[14];
    const float* ff2_b = (const float*)d_in[15];
    const float* lnf_g = (const float*)d_in[16];
    const float* lnf_b = (const float*)d_in[17];

    char* ws = (char*)d_ws;
    float*          h     = (float*)ws;                        // [0, 8M)
    __hip_bfloat16* qkvd0 = (__hip_bfloat16*)(ws + 8388608);   // 12.6 MB
    __hip_bfloat16* qkvd1 = (__hip_bfloat16*)(ws + 20971520);  // 12.6 MB
    __hip_bfloat16* wb    = (__hip_bfloat16*)(ws + 33554432);  // weights bf16 (~5 MB)

    __hip_bfloat16* w_out_b = wb + 65536;
    __hip_bfloat16* qkv_w_b = wb + 131072;
    __hip_bfloat16* out_w_b = wb + 720896;
    __hip_bfloat16* ff1_w_b = wb + 917504;
    __hip_bfloat16* ff2_w_b = wb + 1703936;

    cvt_all<<<1216, dim3(256), 0, stream>>>(w_in, w_out, qkv_w, out_w, ff1_w, ff2_w, wb);

    // embed + LN1_0 + layer-0 qkv (fused)
    embed_qkv<<<dim3(SEQ/32, BATCH), dim3(1024), 0, stream>>>(
        x, wb, ln1_g, ln1_b, qkv_b, h, qkvd0);

    // layer 0: reads qkvd0, tail computes layer-1 qkv into qkvd1
    attn_ffn<1><<<dim3(SEQ/32, BATCH), dim3(1024), 0, stream>>>(
        qkvd0, out_w_b, out_b, h,
        ln2_g, ln2_b, ff1_w_b, ff1_b, ff2_w_b, ff2_b,
        ln1_g + HDIM, ln1_b + HDIM,
        qkv_w_b + (size_t)768*HDIM, qkv_b + 768, nullptr, qkvd1);

    // layer 1: reads qkvd1, tail computes layer-2 qkv into qkvd0
    attn_ffn<1><<<dim3(SEQ/32, BATCH), dim3(1024), 0, stream>>>(
        qkvd1, out_w_b + (size_t)HDIM*HDIM, out_b + HDIM, h,
        ln2_g + HDIM, ln2_b + HDIM,
        ff1_w_b + (size_t)FFN_DIM*HDIM, ff1_b + FFN_DIM,
        ff2_w_b + (size_t)HDIM*FFN_DIM, ff2_b + HDIM,
        ln1_g + 2*HDIM, ln1_b + 2*HDIM,
        qkv_w_b + (size_t)2*768*HDIM, qkv_b + 2*768, nullptr, qkvd0);

    // layer 2: reads qkvd0, tail fuses LNf + out-GEMM (writes d_out)
    attn_ffn<2><<<dim3(SEQ/32, BATCH), dim3(1024), 0, stream>>>(
        qkvd0, out_w_b + (size_t)2*HDIM*HDIM, out_b + 2*HDIM, h,
        ln2_g + 2*HDIM, ln2_b + 2*HDIM,
        ff1_w_b + (size_t)2*FFN_DIM*HDIM, ff1_b + 2*FFN_DIM,
        ff2_w_b + (size_t)2*HDIM*FFN_DIM, ff2_b + 2*HDIM,
        lnf_g, lnf_b, w_out_b, b_out, (float*)d_out, nullptr);
}